// Round 3
// baseline (184.339 us; speedup 1.0000x reference)
//
#include <hip/hip_runtime.h>
#include <stdint.h>

// EMA along contiguous T axis — register-prefetch pipelined version.
// (Resubmission of R2: bench infra failed before running; kernel re-audited
// for hangs/faults — barriers uniform, LDS/global bounds and alignment OK,
// all tile LDS traffic single-wave-owned.)
//
// R1 post-mortem: global_load_lds (writes LDS = tracked memory state) mixed
// with "memory"-clobbered asm forces the waitcnt legalizer to insert its own
// vmcnt(0) drains -> the hand ledger never pipelined (61.9us ~= R0's 60.5us,
// VALUBusy fell to 5%). Also KPT=24 (96B stride) caused a 16-way b128 bank
// conflict (1.18M counter).
//
// This version has ZERO inline asm and ZERO global_load_lds:
//  - prefetch seq s+1 into 24 VGPRs (plain dwordx4 loads; register loads are
//    not memory state, so the compiler places exactly one optimal vmcnt wait
//    at first use = the LDS deposit of the next iteration)
//  - all LDS traffic is wave-local (deposit/read/write/read of the wave's own
//    region; same-wave DS ops are in-order -> no barriers for staging)
//  - exactly ONE __syncthreads per sequence (3-float wave-aggregate exchange,
//    double-buffered), placed where no loads are in flight by construction
//  - chunks padded to 28 words (112B): 16B-aligned for b128, bank starts
//    stride 28 mod 32 -> 2-way max (free) on the strided side
//
// Grid: ceil(nseq/4) = 1028 blocks, ns = 4 each, all resident (~4 blocks/CU
// at 28.7KB LDS) -> 3 of 4 sequences fully prefetch-covered per block.

constexpr int T_LEN = 6000;
constexpr int KPT   = 24;                 // elements per chunk (thread)
constexpr int NCH   = T_LEN / KPT;        // 250 chunks
constexpr int BLOCK = 256;                // 4 waves
constexpr int CHW   = 28;                 // padded words per chunk (112B)
constexpr int G4    = T_LEN / 4;          // 1500 float4 granules

typedef float f32x4 __attribute__((ext_vector_type(4)));

__global__ __launch_bounds__(BLOCK) void ema_kernel(
    const float* __restrict__ x, const float* __restrict__ init,
    const float* __restrict__ wptr, float* __restrict__ out, int nseq)
{
    __shared__ __align__(16) float lds[256 * CHW];   // 28672 B
    __shared__ float waveB[2][4];

    const int tid  = threadIdx.x;
    const int lane = tid & 63;
    const int wid  = tid >> 6;
    const int bid  = blockIdx.x;
    const int G    = gridDim.x;
    const int ns   = (nseq - bid + G - 1) / G;       // <= 4 by launcher choice
    if (ns <= 0) return;

    const float w = fminf(fmaxf(wptr[0], 0.0f), 1.0f);
    const float d = 1.0f - w;

    // ---- data-independent constants ----
    float pw8[8];                       // d^(j+1), j=0..7
    { float p = d;
      #pragma unroll
      for (int j = 0; j < 8; ++j) { pw8[j] = p; p *= d; } }
    const float d8 = pw8[7];            // d^8
    const float q  = d8 * d8 * d8;      // d^24: per-chunk decay
    float qp[8];                        // q^(2^k)
    qp[0] = q;
    #pragma unroll
    for (int k = 1; k < 8; ++k) qp[k] = qp[k-1] * qp[k-1];
    const float q64 = qp[6];
    float qlane = 1.0f;                 // q^lane
    #pragma unroll
    for (int k = 0; k < 6; ++k) if ((lane >> k) & 1) qlane *= qp[k];
    float qtid = qlane;                 // q^tid
    if (wid & 1) qtid *= qp[6];
    if (wid & 2) qtid *= qp[7];

    // ---- initial states (ns <= 4) ----
    float i0 = init[bid];
    float i1 = (ns > 1) ? init[bid + G]     : 0.0f;
    float i2 = (ns > 2) ? init[bid + 2 * G] : 0.0f;
    float i3 = (ns > 3) ? init[bid + 3 * G] : 0.0f;

    // ---- per-lane coalesced-granule constants ----
    // wave w owns granules [384w, 384w+384) = chunks [64w, 64w+64)
    const int g0 = wid * 384 + lane;
    int  woff[6];                       // padded LDS word addr of granule
    bool gok[6];
    #pragma unroll
    for (int i = 0; i < 6; ++i) {
        const int g = g0 + 64 * i;
        gok[i]  = (g < G4);
        woff[i] = CHW * (g / 6) + 4 * (g % 6);   // byte 112c+16j: 16B-aligned
    }
    const bool act   = (tid < NCH);
    const int  cbase = CHW * tid;       // this thread's chunk base word

    // ---- prologue: prefetch seq 0 into registers ----
    f32x4 r0, r1, r2, r3, r4, r5;
    {
        const f32x4* xs4 = (const f32x4*)(x + (size_t)bid * T_LEN);
        if (gok[0]) r0 = xs4[g0];
        if (gok[1]) r1 = xs4[g0 + 64];
        if (gok[2]) r2 = xs4[g0 + 128];
        if (gok[3]) r3 = xs4[g0 + 192];
        if (gok[4]) r4 = xs4[g0 + 256];
        if (gok[5]) r5 = xs4[g0 + 320];
    }

    for (int s = 0; s < ns; ++s) {
        const int seq = bid + s * G;

        // ---- deposit prefetched registers into padded LDS (wave-local) ----
        // (compiler inserts the single vmcnt wait for the loads right here)
        if (gok[0]) *(f32x4*)&lds[woff[0]] = r0;
        if (gok[1]) *(f32x4*)&lds[woff[1]] = r1;
        if (gok[2]) *(f32x4*)&lds[woff[2]] = r2;
        if (gok[3]) *(f32x4*)&lds[woff[3]] = r3;
        if (gok[4]) *(f32x4*)&lds[woff[4]] = r4;
        if (gok[5]) *(f32x4*)&lds[woff[5]] = r5;

        // ---- per-chunk prefix chain: B_j = d*B_{j-1} + w*x_j ----
        float Bv[KPT];
        float bagg = 0.0f;
        if (act) {
            const f32x4 c0 = *(const f32x4*)&lds[cbase];
            const f32x4 c1 = *(const f32x4*)&lds[cbase + 4];
            const f32x4 c2 = *(const f32x4*)&lds[cbase + 8];
            const f32x4 c3 = *(const f32x4*)&lds[cbase + 12];
            const f32x4 c4 = *(const f32x4*)&lds[cbase + 16];
            const f32x4 c5 = *(const f32x4*)&lds[cbase + 20];
            float xv[KPT];
            xv[0]=c0.x;  xv[1]=c0.y;  xv[2]=c0.z;  xv[3]=c0.w;
            xv[4]=c1.x;  xv[5]=c1.y;  xv[6]=c1.z;  xv[7]=c1.w;
            xv[8]=c2.x;  xv[9]=c2.y;  xv[10]=c2.z; xv[11]=c2.w;
            xv[12]=c3.x; xv[13]=c3.y; xv[14]=c3.z; xv[15]=c3.w;
            xv[16]=c4.x; xv[17]=c4.y; xv[18]=c4.z; xv[19]=c4.w;
            xv[20]=c5.x; xv[21]=c5.y; xv[22]=c5.z; xv[23]=c5.w;
            float acc = 0.0f;
            #pragma unroll
            for (int j = 0; j < KPT; ++j) { acc = fmaf(d, acc, w * xv[j]); Bv[j] = acc; }
            bagg = acc;
        }

        // ---- wave-level inclusive scan of chunk aggregates (A analytic) ----
        float b = bagg;
        #pragma unroll
        for (int k = 0; k < 6; ++k) {
            const float pb = __shfl_up(b, 1u << k, 64);
            if (lane >= (1 << k)) b = fmaf(qp[k], pb, b);
        }
        if (lane == 63) waveB[s & 1][wid] = b;
        __syncthreads();                       // the only barrier per sequence
        const float wb0 = waveB[s & 1][0];
        const float wb1 = waveB[s & 1][1];
        const float wb2 = waveB[s & 1][2];
        float pB = 0.0f;
        if (wid > 0) pB = wb0;
        if (wid > 1) pB = fmaf(q64, pB, wb1);
        if (wid > 2) pB = fmaf(q64, pB, wb2);

        float eb = __shfl_up(b, 1, 64);
        if (lane == 0) eb = 0.0f;
        const float Bex = fmaf(qlane, pB, eb);
        const float s0  = (s == 0) ? i0 : (s == 1) ? i1 : (s == 2) ? i2 : i3;
        const float sin_ = fmaf(qtid, s0, Bex);

        // ---- prefetch next sequence (after the barrier: stays in flight
        //      across fixup + LDS round-trip + stores + next chain) ----
        if (s + 1 < ns) {
            const f32x4* nx4 = (const f32x4*)(x + (size_t)(seq + G) * T_LEN);
            if (gok[0]) r0 = nx4[g0];
            if (gok[1]) r1 = nx4[g0 + 64];
            if (gok[2]) r2 = nx4[g0 + 128];
            if (gok[3]) r3 = nx4[g0 + 192];
            if (gok[4]) r4 = nx4[g0 + 256];
            if (gok[5]) r5 = nx4[g0 + 320];
        }

        // ---- fixup out_j = d^(j+1)*sin + B_j, strided write (wave-local) ----
        if (act) {
            const float b0 = sin_;
            const float b1 = b0 * d8;
            const float b2 = b1 * d8;
            f32x4 oA = { fmaf(pw8[0],b0,Bv[0]),  fmaf(pw8[1],b0,Bv[1]),
                         fmaf(pw8[2],b0,Bv[2]),  fmaf(pw8[3],b0,Bv[3]) };
            f32x4 oB = { fmaf(pw8[4],b0,Bv[4]),  fmaf(pw8[5],b0,Bv[5]),
                         fmaf(pw8[6],b0,Bv[6]),  fmaf(pw8[7],b0,Bv[7]) };
            f32x4 oC = { fmaf(pw8[0],b1,Bv[8]),  fmaf(pw8[1],b1,Bv[9]),
                         fmaf(pw8[2],b1,Bv[10]), fmaf(pw8[3],b1,Bv[11]) };
            f32x4 oD = { fmaf(pw8[4],b1,Bv[12]), fmaf(pw8[5],b1,Bv[13]),
                         fmaf(pw8[6],b1,Bv[14]), fmaf(pw8[7],b1,Bv[15]) };
            f32x4 oE = { fmaf(pw8[0],b2,Bv[16]), fmaf(pw8[1],b2,Bv[17]),
                         fmaf(pw8[2],b2,Bv[18]), fmaf(pw8[3],b2,Bv[19]) };
            f32x4 oF = { fmaf(pw8[4],b2,Bv[20]), fmaf(pw8[5],b2,Bv[21]),
                         fmaf(pw8[6],b2,Bv[22]), fmaf(pw8[7],b2,Bv[23]) };
            *(f32x4*)&lds[cbase]      = oA;
            *(f32x4*)&lds[cbase + 4]  = oB;
            *(f32x4*)&lds[cbase + 8]  = oC;
            *(f32x4*)&lds[cbase + 12] = oD;
            *(f32x4*)&lds[cbase + 16] = oE;
            *(f32x4*)&lds[cbase + 20] = oF;
        }

        // ---- coalesced read-back + store (wave-local, same-wave in-order) ----
        {
            f32x4* os4 = (f32x4*)(out + (size_t)seq * T_LEN);
            if (gok[0]) os4[g0]       = *(const f32x4*)&lds[woff[0]];
            if (gok[1]) os4[g0 + 64]  = *(const f32x4*)&lds[woff[1]];
            if (gok[2]) os4[g0 + 128] = *(const f32x4*)&lds[woff[2]];
            if (gok[3]) os4[g0 + 192] = *(const f32x4*)&lds[woff[3]];
            if (gok[4]) os4[g0 + 256] = *(const f32x4*)&lds[woff[4]];
            if (gok[5]) os4[g0 + 320] = *(const f32x4*)&lds[woff[5]];
        }
    }
}

extern "C" void kernel_launch(void* const* d_in, const int* in_sizes, int n_in,
                              void* d_out, int out_size, void* d_ws, size_t ws_size,
                              hipStream_t stream) {
    const float* mag_spec = (const float*)d_in[0];
    const float* initial_state = (const float*)d_in[1];
    const float* weights = (const float*)d_in[2];
    float* out = (float*)d_out;

    const int nseq = in_sizes[1];       // 8*2*257 = 4112

    int G = (nseq + 3) / 4;             // ns = 4 exactly for 4112 -> 1028 blocks
    if (G < 1) G = 1;
    if (G > nseq) G = nseq;

    ema_kernel<<<G, BLOCK, 0, stream>>>(mag_spec, initial_state, weights, out, nseq);
}

// Round 4
// 178.143 us; speedup vs baseline: 1.0348x; 1.0348x over previous
//
#include <hip/hip_runtime.h>
#include <stdint.h>

// EMA along contiguous T axis — dual-prologue-prefetch version.
//
// R3 post-mortem: kernel runs exactly at achieved-BW (768KB/CU at 9 GB/s/CU
// = observed 161k cy). Achieved BW is concurrency-limited (Little's law:
// need ~10KB/CU in flight at ~1000cy loaded latency; R3 averaged ~5KB/CU
// because loads were in flight only ~35% of each iteration and only ~2.5-4
// blocks/CU were resident). Bank conflicts (1.15M) are 3% of CU cycles —
// a non-factor.
//
// This version: ns=2, grid=ceil(nseq/2)=2056 (8 blocks/CU nominal, 5
// resident at 28.7KB LDS). BOTH sequences prefetched in the prologue
// (12 dwordx4/lane, 48KB/block outstanding before any wait): seq-1 loads
// stay in flight across seq-0's whole compute phase, and block churn keeps
// prologue bursts of new blocks overlapping compute of old ones.
// LDS layout identical to R3 (CHW=28: 16B alignment required by b128;
// wave-local staging, one barrier per sequence).

constexpr int T_LEN = 6000;
constexpr int KPT   = 24;                 // elements per chunk (thread)
constexpr int NCH   = T_LEN / KPT;        // 250 chunks
constexpr int BLOCK = 256;                // 4 waves
constexpr int CHW   = 28;                 // padded words per chunk (112B, 16B-aligned)
constexpr int G4    = T_LEN / 4;          // 1500 float4 granules

typedef float f32x4 __attribute__((ext_vector_type(4)));

__global__ __launch_bounds__(BLOCK) void ema_kernel(
    const float* __restrict__ x, const float* __restrict__ init,
    const float* __restrict__ wptr, float* __restrict__ out, int nseq)
{
    __shared__ __align__(16) float lds[256 * CHW];   // 28672 B
    __shared__ float waveB[2][4];

    const int tid  = threadIdx.x;
    const int lane = tid & 63;
    const int wid  = tid >> 6;
    const int bid  = blockIdx.x;
    const int G    = gridDim.x;
    const int ns   = (nseq - bid + G - 1) / G;       // <= 2 by launcher choice
    if (ns <= 0) return;

    const float w = fminf(fmaxf(wptr[0], 0.0f), 1.0f);
    const float d = 1.0f - w;

    // ---- data-independent constants ----
    float pw8[8];                       // d^(j+1), j=0..7
    { float p = d;
      #pragma unroll
      for (int j = 0; j < 8; ++j) { pw8[j] = p; p *= d; } }
    const float d8 = pw8[7];            // d^8
    const float q  = d8 * d8 * d8;      // d^24: per-chunk decay
    float qp[8];                        // q^(2^k)
    qp[0] = q;
    #pragma unroll
    for (int k = 1; k < 8; ++k) qp[k] = qp[k-1] * qp[k-1];
    const float q64 = qp[6];
    float qlane = 1.0f;                 // q^lane
    #pragma unroll
    for (int k = 0; k < 6; ++k) if ((lane >> k) & 1) qlane *= qp[k];
    float qtid = qlane;                 // q^tid
    if (wid & 1) qtid *= qp[6];
    if (wid & 2) qtid *= qp[7];

    // ---- initial states (ns <= 2) ----
    const float i0 = init[bid];
    const float i1 = (ns > 1) ? init[bid + G] : 0.0f;

    // ---- per-lane coalesced-granule constants ----
    // wave w owns granules [384w, 384w+384) = chunks [64w, 64w+64)
    const int g0 = wid * 384 + lane;
    int  woff[6];                       // padded LDS word addr of granule
    bool gok[6];
    #pragma unroll
    for (int i = 0; i < 6; ++i) {
        const int g = g0 + 64 * i;
        gok[i]  = (g < G4);
        woff[i] = CHW * (g / 6) + 4 * (g % 6);   // byte 112c+16j: 16B-aligned
    }
    const bool act   = (tid < NCH);
    const int  cbase = CHW * tid;       // this thread's chunk base word

    // ---- prologue: prefetch BOTH sequences into registers (48KB/block
    //      outstanding before any wait) ----
    f32x4 r0, r1, r2, r3, r4, r5;       // seq 0
    f32x4 p0, p1, p2, p3, p4, p5;       // seq 1
    {
        const f32x4* xs4 = (const f32x4*)(x + (size_t)bid * T_LEN);
        if (gok[0]) r0 = xs4[g0];
        if (gok[1]) r1 = xs4[g0 + 64];
        if (gok[2]) r2 = xs4[g0 + 128];
        if (gok[3]) r3 = xs4[g0 + 192];
        if (gok[4]) r4 = xs4[g0 + 256];
        if (gok[5]) r5 = xs4[g0 + 320];
    }
    if (ns > 1) {
        const f32x4* nx4 = (const f32x4*)(x + (size_t)(bid + G) * T_LEN);
        if (gok[0]) p0 = nx4[g0];
        if (gok[1]) p1 = nx4[g0 + 64];
        if (gok[2]) p2 = nx4[g0 + 128];
        if (gok[3]) p3 = nx4[g0 + 192];
        if (gok[4]) p4 = nx4[g0 + 256];
        if (gok[5]) p5 = nx4[g0 + 320];
    }

    // ---- per-sequence body (inlined twice; all indices compile-time) ----
    auto body = [&](int sb, int seq, float s0,
                    const f32x4& a0, const f32x4& a1, const f32x4& a2,
                    const f32x4& a3, const f32x4& a4, const f32x4& a5) {
        // deposit prefetched registers into padded LDS (wave-local).
        // Compiler inserts the minimal counted vmcnt wait here (younger
        // loads/stores stay outstanding).
        if (gok[0]) *(f32x4*)&lds[woff[0]] = a0;
        if (gok[1]) *(f32x4*)&lds[woff[1]] = a1;
        if (gok[2]) *(f32x4*)&lds[woff[2]] = a2;
        if (gok[3]) *(f32x4*)&lds[woff[3]] = a3;
        if (gok[4]) *(f32x4*)&lds[woff[4]] = a4;
        if (gok[5]) *(f32x4*)&lds[woff[5]] = a5;

        // per-chunk prefix chain: B_j = d*B_{j-1} + w*x_j
        float Bv[KPT];
        float bagg = 0.0f;
        if (act) {
            const f32x4 c0 = *(const f32x4*)&lds[cbase];
            const f32x4 c1 = *(const f32x4*)&lds[cbase + 4];
            const f32x4 c2 = *(const f32x4*)&lds[cbase + 8];
            const f32x4 c3 = *(const f32x4*)&lds[cbase + 12];
            const f32x4 c4 = *(const f32x4*)&lds[cbase + 16];
            const f32x4 c5 = *(const f32x4*)&lds[cbase + 20];
            float xv[KPT];
            xv[0]=c0.x;  xv[1]=c0.y;  xv[2]=c0.z;  xv[3]=c0.w;
            xv[4]=c1.x;  xv[5]=c1.y;  xv[6]=c1.z;  xv[7]=c1.w;
            xv[8]=c2.x;  xv[9]=c2.y;  xv[10]=c2.z; xv[11]=c2.w;
            xv[12]=c3.x; xv[13]=c3.y; xv[14]=c3.z; xv[15]=c3.w;
            xv[16]=c4.x; xv[17]=c4.y; xv[18]=c4.z; xv[19]=c4.w;
            xv[20]=c5.x; xv[21]=c5.y; xv[22]=c5.z; xv[23]=c5.w;
            float acc = 0.0f;
            #pragma unroll
            for (int j = 0; j < KPT; ++j) { acc = fmaf(d, acc, w * xv[j]); Bv[j] = acc; }
            bagg = acc;
        }

        // wave-level inclusive scan of chunk aggregates (A analytic)
        float b = bagg;
        #pragma unroll
        for (int k = 0; k < 6; ++k) {
            const float pb = __shfl_up(b, 1u << k, 64);
            if (lane >= (1 << k)) b = fmaf(qp[k], pb, b);
        }
        if (lane == 63) waveB[sb][wid] = b;
        __syncthreads();                       // the only barrier per sequence
        const float wb0 = waveB[sb][0];
        const float wb1 = waveB[sb][1];
        const float wb2 = waveB[sb][2];
        float pB = 0.0f;
        if (wid > 0) pB = wb0;
        if (wid > 1) pB = fmaf(q64, pB, wb1);
        if (wid > 2) pB = fmaf(q64, pB, wb2);

        float eb = __shfl_up(b, 1, 64);
        if (lane == 0) eb = 0.0f;
        const float Bex  = fmaf(qlane, pB, eb);
        const float sin_ = fmaf(qtid, s0, Bex);

        // fixup out_j = d^(j+1)*sin + B_j, strided write (wave-local)
        if (act) {
            const float b0 = sin_;
            const float b1 = b0 * d8;
            const float b2 = b1 * d8;
            f32x4 oA = { fmaf(pw8[0],b0,Bv[0]),  fmaf(pw8[1],b0,Bv[1]),
                         fmaf(pw8[2],b0,Bv[2]),  fmaf(pw8[3],b0,Bv[3]) };
            f32x4 oB = { fmaf(pw8[4],b0,Bv[4]),  fmaf(pw8[5],b0,Bv[5]),
                         fmaf(pw8[6],b0,Bv[6]),  fmaf(pw8[7],b0,Bv[7]) };
            f32x4 oC = { fmaf(pw8[0],b1,Bv[8]),  fmaf(pw8[1],b1,Bv[9]),
                         fmaf(pw8[2],b1,Bv[10]), fmaf(pw8[3],b1,Bv[11]) };
            f32x4 oD = { fmaf(pw8[4],b1,Bv[12]), fmaf(pw8[5],b1,Bv[13]),
                         fmaf(pw8[6],b1,Bv[14]), fmaf(pw8[7],b1,Bv[15]) };
            f32x4 oE = { fmaf(pw8[0],b2,Bv[16]), fmaf(pw8[1],b2,Bv[17]),
                         fmaf(pw8[2],b2,Bv[18]), fmaf(pw8[3],b2,Bv[19]) };
            f32x4 oF = { fmaf(pw8[4],b2,Bv[20]), fmaf(pw8[5],b2,Bv[21]),
                         fmaf(pw8[6],b2,Bv[22]), fmaf(pw8[7],b2,Bv[23]) };
            *(f32x4*)&lds[cbase]      = oA;
            *(f32x4*)&lds[cbase + 4]  = oB;
            *(f32x4*)&lds[cbase + 8]  = oC;
            *(f32x4*)&lds[cbase + 12] = oD;
            *(f32x4*)&lds[cbase + 16] = oE;
            *(f32x4*)&lds[cbase + 20] = oF;
        }

        // coalesced read-back + store (wave-local, same-wave in-order)
        {
            f32x4* os4 = (f32x4*)(out + (size_t)seq * T_LEN);
            if (gok[0]) os4[g0]       = *(const f32x4*)&lds[woff[0]];
            if (gok[1]) os4[g0 + 64]  = *(const f32x4*)&lds[woff[1]];
            if (gok[2]) os4[g0 + 128] = *(const f32x4*)&lds[woff[2]];
            if (gok[3]) os4[g0 + 192] = *(const f32x4*)&lds[woff[3]];
            if (gok[4]) os4[g0 + 256] = *(const f32x4*)&lds[woff[4]];
            if (gok[5]) os4[g0 + 320] = *(const f32x4*)&lds[woff[5]];
        }
    };

    body(0, bid, i0, r0, r1, r2, r3, r4, r5);
    if (ns > 1)
        body(1, bid + G, i1, p0, p1, p2, p3, p4, p5);
}

extern "C" void kernel_launch(void* const* d_in, const int* in_sizes, int n_in,
                              void* d_out, int out_size, void* d_ws, size_t ws_size,
                              hipStream_t stream) {
    const float* mag_spec = (const float*)d_in[0];
    const float* initial_state = (const float*)d_in[1];
    const float* weights = (const float*)d_in[2];
    float* out = (float*)d_out;

    const int nseq = in_sizes[1];       // 8*2*257 = 4112

    int G = (nseq + 1) / 2;             // ns = 2 -> 2056 blocks
    if (G < 1) G = 1;
    if (G > nseq) G = nseq;

    ema_kernel<<<G, BLOCK, 0, stream>>>(mag_spec, initial_state, weights, out, nseq);
}